// Round 9
// baseline (425.235 us; speedup 1.0000x reference)
//
#include <hip/hip_runtime.h>

typedef float f4 __attribute__((ext_vector_type(4)));
typedef unsigned short u16;
typedef unsigned char u8;
typedef u16 us4 __attribute__((ext_vector_type(4)));
typedef int i4 __attribute__((ext_vector_type(4)));
typedef __attribute__((ext_vector_type(4))) float f32x4;
typedef __attribute__((ext_vector_type(8))) short bf16x8;

#define DIM 128
#define DIM4 32
#define NB_S 8     // src slices (== #XCDs)
#define NB_D 16    // dst slices per src slice
#define NB 128     // total buckets

__device__ __forceinline__ u16 f32_to_bf16_rne(float f) {
  unsigned u = __float_as_uint(f);
  return (u16)((u + 0x7FFFu + ((u >> 16) & 1u)) >> 16);
}
__device__ __forceinline__ us4 f4_to_bf4(f4 v) {
  us4 h;
  h[0] = f32_to_bf16_rne(v[0]); h[1] = f32_to_bf16_rne(v[1]);
  h[2] = f32_to_bf16_rne(v[2]); h[3] = f32_to_bf16_rne(v[3]);
  return h;
}

// ---------------- Kernel A: MFMA transform + fused u8 quant ----------------
template <bool QUANT>
__global__ __launch_bounds__(256) void transform_mfma(
    const float* __restrict__ x, const float* __restrict__ Wt,
    const float* __restrict__ bt, const float* __restrict__ Ws,
    float* __restrict__ self_out, unsigned* __restrict__ qt,
    float* __restrict__ sc, float* __restrict__ z, int N) {
  __shared__ u16 Wb[DIM * DIM];
  __shared__ u16 Xb[64 * DIM];

  const int tid = threadIdx.x;
  const int base = blockIdx.x * 64;

  const f4* Wt4 = (const f4*)Wt;
  for (int i = tid; i < DIM * DIM4; i += 256) {
    int row = i >> 5, k4 = i & 31;
    *(us4*)&Wb[((row * DIM + k4 * 4) ^ ((row & 7) << 3))] = f4_to_bf4(Wt4[i]);
  }
  const f4* xg4 = (const f4*)x;
  for (int i = tid; i < 64 * DIM4; i += 256) {
    int row = i >> 5, k4 = i & 31;
    int g = base + row;
    f4 v = {0.f, 0.f, 0.f, 0.f};
    if (g < N) v = __builtin_nontemporal_load(&xg4[(size_t)g * DIM4 + k4]);
    *(us4*)&Xb[((row * DIM + k4 * 4) ^ ((row & 7) << 3))] = f4_to_bf4(v);
  }
  __syncthreads();

  const int lane = tid & 63;
  const int w = tid >> 6;
  const int rA = lane & 15;
  const int part = lane >> 4;

  f32x4 acc[8];
#pragma unroll
  for (int c = 0; c < 8; ++c) acc[c] = (f32x4){0.f, 0.f, 0.f, 0.f};

  const int xrow = w * 16 + rA;
  const int xswz = (xrow & 7) << 3;
#pragma unroll
  for (int s = 0; s < 4; ++s) {
    const int kofs = s * 32 + part * 8;
    bf16x8 a = *(const bf16x8*)&Xb[((xrow * DIM + kofs) ^ xswz)];
#pragma unroll
    for (int c = 0; c < 8; ++c) {
      const int wrow = c * 16 + rA;
      bf16x8 b = *(const bf16x8*)&Wb[((wrow * DIM + kofs) ^ ((wrow & 7) << 3))];
      acc[c] = __builtin_amdgcn_mfma_f32_16x16x32_bf16(a, b, acc[c], 0, 0, 0);
    }
  }

  float btv[8], wsv[8];
#pragma unroll
  for (int c = 0; c < 8; ++c) {
    btv[c] = bt[c * 16 + rA];
    wsv[c] = Ws[c * 16 + rA];
  }

  float vv[4][8];
#pragma unroll
  for (int r = 0; r < 4; ++r)
#pragma unroll
    for (int c = 0; c < 8; ++c) vv[r][c] = 2.0f * acc[c][r] + btv[c];

#pragma unroll
  for (int r = 0; r < 4; ++r) {
    int g = base + w * 16 + part * 4 + r;
    if (g < N) {
      float zp = 0.f;
#pragma unroll
      for (int c = 0; c < 8; ++c) {
        self_out[(size_t)g * DIM + c * 16 + rA] = vv[r][c];
        zp += vv[r][c] * wsv[c];
      }
      zp += __shfl_xor(zp, 8);
      zp += __shfl_xor(zp, 4);
      zp += __shfl_xor(zp, 2);
      zp += __shfl_xor(zp, 1);
      if (rA == 0 && z != nullptr) z[g] = zp;
    }
  }

  if constexpr (QUANT) {
    __syncthreads();
    u8* Qb = (u8*)Xb;
#pragma unroll
    for (int r = 0; r < 4; ++r) {
      const int rr = w * 16 + part * 4 + r;
      const int g = base + rr;
      float m = 0.f;
#pragma unroll
      for (int c = 0; c < 8; ++c) m = fmaxf(m, fabsf(vv[r][c]));
      m = fmaxf(m, __shfl_xor(m, 8));
      m = fmaxf(m, __shfl_xor(m, 4));
      m = fmaxf(m, __shfl_xor(m, 2));
      m = fmaxf(m, __shfl_xor(m, 1));
      const float inv = (m > 0.f) ? 127.0f / m : 0.f;
#pragma unroll
      for (int c = 0; c < 8; ++c) {
        int qv = __float2int_rn(vv[r][c] * inv) + 128;
        Qb[rr * DIM + c * 16 + rA] = (u8)qv;
      }
      if (rA == 0 && g < N) sc[g] = m * (1.0f / 127.0f);
    }
    __syncthreads();
    for (int i = tid; i < 64 * DIM4; i += 256) {
      int row = i >> 5, c4 = i & 31;
      int g = base + row;
      if (g < N)
        qt[(size_t)g * DIM4 + c4] = *(const unsigned*)&Qb[row * DIM + c4 * 4];
    }
  }
}

// ---------------- Bucketing pre-pass ----------------
// K1: global histogram of (src-slice, dst-slice) buckets.
__global__ __launch_bounds__(256) void count_kernel(
    const int* __restrict__ ei, int* __restrict__ bins, int E, int N) {
  __shared__ int h[NB];
  for (int i = threadIdx.x; i < NB; i += 256) h[i] = 0;
  __syncthreads();
  const unsigned divs = (unsigned)((N + NB_S - 1) / NB_S);
  const unsigned divd = (unsigned)((N + NB_D - 1) / NB_D);
  const int per = (E + gridDim.x - 1) / gridDim.x;
  const int lo = blockIdx.x * per;
  const int hi = min(E, lo + per);
  for (int e = lo + threadIdx.x; e < hi; e += 256) {
    unsigned s = (unsigned)__builtin_nontemporal_load(&ei[e]);
    unsigned d = (unsigned)__builtin_nontemporal_load(&ei[E + e]);
    int b = (int)(s / divs) * NB_D + (int)(d / divd);
    atomicAdd(&h[b], 1);
  }
  __syncthreads();
  for (int i = threadIdx.x; i < NB; i += 256)
    if (h[i]) atomicAdd(&bins[i], h[i]);
}

// K2: exclusive scan (tiny) -> offsets, init cursors.
__global__ void scan_kernel(const int* __restrict__ bins,
                            int* __restrict__ offsets,
                            int* __restrict__ cursors) {
  if (blockIdx.x == 0 && threadIdx.x == 0) {
    int acc = 0;
    for (int i = 0; i < NB; ++i) {
      offsets[i] = acc;
      cursors[i] = acc;
      acc += bins[i];
    }
    offsets[NB] = acc;
  }
}

// K3: scatter edges into bucket-ordered record arrays; also computes esc
// (z is ready; esc writes are sequential in original edge order).
__global__ __launch_bounds__(256) void scatter_kernel(
    const int* __restrict__ ei, const float* __restrict__ z,
    const float* __restrict__ bs, float* __restrict__ esc,
    int* __restrict__ srcs, int* __restrict__ dsts, int* __restrict__ eids,
    int* __restrict__ cursors, int E, int N) {
  __shared__ int h[NB];
  __shared__ int basep[NB];
  for (int i = threadIdx.x; i < NB; i += 256) h[i] = 0;
  __syncthreads();
  const unsigned divs = (unsigned)((N + NB_S - 1) / NB_S);
  const unsigned divd = (unsigned)((N + NB_D - 1) / NB_D);
  const float b0 = bs[0];
  const int per = (E + gridDim.x - 1) / gridDim.x;
  const int lo = blockIdx.x * per;
  const int hi = min(E, lo + per);
  for (int e = lo + threadIdx.x; e < hi; e += 256) {
    unsigned s = (unsigned)ei[e];
    unsigned d = (unsigned)ei[E + e];
    int b = (int)(s / divs) * NB_D + (int)(d / divd);
    atomicAdd(&h[b], 1);
  }
  __syncthreads();
  for (int i = threadIdx.x; i < NB; i += 256) {
    int c = h[i];
    basep[i] = c ? atomicAdd(&cursors[i], c) : 0;
    h[i] = 0;   // reuse as local cursor
  }
  __syncthreads();
  for (int e = lo + threadIdx.x; e < hi; e += 256) {
    int s = ei[e];
    int d = ei[E + e];
    int b = (int)((unsigned)s / divs) * NB_D + (int)((unsigned)d / divd);
    int slot = basep[b] + atomicAdd(&h[b], 1);
    srcs[slot] = s;
    dsts[slot] = d;
    eids[slot] = e;
    float p = 0.5f * (z[s] + z[d]) + b0;
    esc[e] = 1.0f / (1.0f + __expf(-p));
  }
}

// K4: bucketed edge kernel. Block's src-slice = bid%8 (XCD-aligned); all
// blocks sweep dst-slices j=0..15 in the same order -> per-XCD L2 working
// set ~2.4 MB -> gathers hit L2. Records read NT (no-allocate). merged rows
// NT-stored at their original edge positions (512 B chunks).
__global__ __launch_bounds__(256) void edge_bucketed(
    const int* __restrict__ srcs, const int* __restrict__ dsts,
    const int* __restrict__ eids, const unsigned* __restrict__ qt,
    const float* __restrict__ sc, const int* __restrict__ offsets,
    const int* __restrict__ bins, f4* __restrict__ m4) {
  const int lane = threadIdx.x & 31;
  const int grp  = threadIdx.x >> 5;
  const int myx  = blockIdx.x & 7;
  const int r    = blockIdx.x >> 3;
  const int NR   = gridDim.x >> 3;

  for (int j = 0; j < NB_D; ++j) {
    const int b = myx * NB_D + j;
    const int off = offsets[b];
    const int len = bins[b];
    const int lo = off + (int)((long long)len * r / NR);
    const int hi = off + (int)((long long)len * (r + 1) / NR);

    for (int idx = lo + grp * 8; idx < hi; idx += 64) {
      const int cnt = min(8, hi - idx);
      int ss[8], dd[8], ee[8];
#pragma unroll
      for (int u = 0; u < 8; ++u) {
        if (u < cnt) {
          ss[u] = __builtin_nontemporal_load(&srcs[idx + u]);
          dd[u] = __builtin_nontemporal_load(&dsts[idx + u]);
          ee[u] = __builtin_nontemporal_load(&eids[idx + u]);
        } else {
          ss[u] = ss[0]; dd[u] = dd[0]; ee[u] = ee[0];
        }
      }
      unsigned ua[8], ub[8];
      float sa[8], sb[8];
#pragma unroll
      for (int u = 0; u < 8; ++u) {
        ua[u] = qt[(size_t)ss[u] * DIM4 + lane];
        ub[u] = qt[(size_t)dd[u] * DIM4 + lane];
      }
#pragma unroll
      for (int u = 0; u < 8; ++u) {
        sa[u] = 0.5f * sc[ss[u]];
        sb[u] = 0.5f * sc[dd[u]];
      }
#pragma unroll
      for (int u = 0; u < 8; ++u) {
        if (u < cnt) {
          const float off2 = -128.0f * (sa[u] + sb[u]);
          f4 m;
          m[0] = fmaf((float)(ua[u] & 0xffu), sa[u],
                      fmaf((float)(ub[u] & 0xffu), sb[u], off2));
          m[1] = fmaf((float)((ua[u] >> 8) & 0xffu), sa[u],
                      fmaf((float)((ub[u] >> 8) & 0xffu), sb[u], off2));
          m[2] = fmaf((float)((ua[u] >> 16) & 0xffu), sa[u],
                      fmaf((float)((ub[u] >> 16) & 0xffu), sb[u], off2));
          m[3] = fmaf((float)(ua[u] >> 24), sa[u],
                      fmaf((float)(ub[u] >> 24), sb[u], off2));
          __builtin_nontemporal_store(m, &m4[(size_t)ee[u] * DIM4 + lane]);
        }
      }
    }
  }
}

// ---------------- Fallback path (r8 config) ----------------
__global__ __launch_bounds__(256) void edge_kernel_q(
    const int* __restrict__ ei, const unsigned* __restrict__ qt,
    const float* __restrict__ sc, const float* __restrict__ zt,
    const float* __restrict__ bs, f4* __restrict__ m4,
    float* __restrict__ esc, int E) {
  const int lane = threadIdx.x & 31;
  const int grp  = threadIdx.x >> 5;
  const float b0 = bs[0];
  const long long gstride = (long long)gridDim.x * 64;

  for (long long base = ((long long)blockIdx.x * 8 + grp) * 8; base < E;
       base += gstride) {
    if (base + 8 <= E) {
      i4 s0 = *(const i4*)&ei[base];
      i4 s1 = *(const i4*)&ei[base + 4];
      i4 d0 = *(const i4*)&ei[E + base];
      i4 d1 = *(const i4*)&ei[E + base + 4];
      int ss[8], dd[8];
#pragma unroll
      for (int u = 0; u < 4; ++u) {
        ss[u] = s0[u]; ss[u + 4] = s1[u];
        dd[u] = d0[u]; dd[u + 4] = d1[u];
      }
      unsigned ua[8], ub[8];
      float sa[8], sb[8], za[8], zb[8];
#pragma unroll
      for (int u = 0; u < 8; ++u) {
        ua[u] = qt[(size_t)ss[u] * DIM4 + lane];
        ub[u] = qt[(size_t)dd[u] * DIM4 + lane];
      }
#pragma unroll
      for (int u = 0; u < 8; ++u) {
        sa[u] = 0.5f * sc[ss[u]];
        sb[u] = 0.5f * sc[dd[u]];
      }
#pragma unroll
      for (int u = 0; u < 8; ++u) {
        za[u] = zt[ss[u]];
        zb[u] = zt[dd[u]];
      }
      float sval[8];
#pragma unroll
      for (int u = 0; u < 8; ++u) {
        float p = 0.5f * (za[u] + zb[u]) + b0;
        sval[u] = 1.0f / (1.0f + __expf(-p));
        const float off = -128.0f * (sa[u] + sb[u]);
        f4 m;
        m[0] = fmaf((float)(ua[u] & 0xffu), sa[u],
                    fmaf((float)(ub[u] & 0xffu), sb[u], off));
        m[1] = fmaf((float)((ua[u] >> 8) & 0xffu), sa[u],
                    fmaf((float)((ub[u] >> 8) & 0xffu), sb[u], off));
        m[2] = fmaf((float)((ua[u] >> 16) & 0xffu), sa[u],
                    fmaf((float)((ub[u] >> 16) & 0xffu), sb[u], off));
        m[3] = fmaf((float)(ua[u] >> 24), sa[u],
                    fmaf((float)(ub[u] >> 24), sb[u], off));
        __builtin_nontemporal_store(m, &m4[(size_t)(base + u) * DIM4 + lane]);
      }
      if (lane == 0) {
        f4 v0 = {sval[0], sval[1], sval[2], sval[3]};
        f4 v1 = {sval[4], sval[5], sval[6], sval[7]};
        *(f4*)&esc[base] = v0;
        *(f4*)&esc[base + 4] = v1;
      }
    } else {
      for (long long e = base; e < E; ++e) {
        int s = ei[e], d = ei[E + e];
        unsigned ua = qt[(size_t)s * DIM4 + lane];
        unsigned ub = qt[(size_t)d * DIM4 + lane];
        float sa = 0.5f * sc[s];
        float sb = 0.5f * sc[d];
        const float off = -128.0f * (sa + sb);
        f4 m;
        m[0] = fmaf((float)(ua & 0xffu), sa, fmaf((float)(ub & 0xffu), sb, off));
        m[1] = fmaf((float)((ua >> 8) & 0xffu), sa,
                    fmaf((float)((ub >> 8) & 0xffu), sb, off));
        m[2] = fmaf((float)((ua >> 16) & 0xffu), sa,
                    fmaf((float)((ub >> 16) & 0xffu), sb, off));
        m[3] = fmaf((float)(ua >> 24), sa, fmaf((float)(ub >> 24), sb, off));
        __builtin_nontemporal_store(m, &m4[(size_t)e * DIM4 + lane]);
        if (lane == 0) {
          float p = 0.5f * (zt[s] + zt[d]) + b0;
          esc[e] = 1.0f / (1.0f + __expf(-p));
        }
      }
    }
  }
}

__global__ __launch_bounds__(256) void edge_kernel_f32(
    const int* __restrict__ ei, const f4* __restrict__ selff4,
    f4* __restrict__ m4, int E) {
  const int lane = threadIdx.x & 31;
  const int grp  = threadIdx.x >> 5;
  const long long gstride = (long long)gridDim.x * 32;
  for (long long base = ((long long)blockIdx.x * 8 + grp) * 4; base < E;
       base += gstride) {
    long long lim = (base + 4 <= E) ? base + 4 : (long long)E;
    for (long long e = base; e < lim; ++e) {
      int s = ei[e], d = ei[E + e];
      f4 a = selff4[(size_t)s * DIM4 + lane];
      f4 b = selff4[(size_t)d * DIM4 + lane];
      f4 m = 0.5f * (a + b);
      __builtin_nontemporal_store(m, &m4[(size_t)e * DIM4 + lane]);
    }
  }
}

__global__ __launch_bounds__(256) void score_dot_kernel(
    const int* __restrict__ ei, const float* __restrict__ self,
    const float* __restrict__ Ws, const float* __restrict__ bs,
    float* __restrict__ esc, int E) {
  const int lane = threadIdx.x & 31;
  const int grp  = threadIdx.x >> 5;
  const f4* self4 = (const f4*)self;
  const f4 w = ((const f4*)Ws)[lane];
  const float b0 = bs[0];
  const long long stride = (long long)gridDim.x * 8;
  for (long long e = (long long)blockIdx.x * 8 + grp; e < E; e += stride) {
    int s = ei[e], d = ei[E + e];
    f4 a = self4[(size_t)s * DIM4 + lane];
    f4 b = self4[(size_t)d * DIM4 + lane];
    f4 m = 0.5f * (a + b);
    float p = m[0]*w[0] + m[1]*w[1] + m[2]*w[2] + m[3]*w[3];
    p += __shfl_xor(p, 16);
    p += __shfl_xor(p, 8);
    p += __shfl_xor(p, 4);
    p += __shfl_xor(p, 2);
    p += __shfl_xor(p, 1);
    if (lane == 0) esc[e] = 1.0f / (1.0f + __expf(-(p + b0)));
  }
}

extern "C" void kernel_launch(void* const* d_in, const int* in_sizes, int n_in,
                              void* d_out, int out_size, void* d_ws, size_t ws_size,
                              hipStream_t stream) {
  const float* x  = (const float*)d_in[0];
  const int*   ei = (const int*)d_in[1];
  // d_in[2] = batch (unused by the outputs)
  const float* Wt = (const float*)d_in[3];
  const float* bt = (const float*)d_in[4];
  const float* Ws = (const float*)d_in[5];
  const float* bs = (const float*)d_in[6];

  const int N = in_sizes[0] / DIM;
  const int E = in_sizes[1] / 2;

  float* merged = (float*)d_out;                       // [E,128]
  float* selfo  = merged + (size_t)E * DIM;            // [N,128]
  float* esc    = selfo + (size_t)N * DIM;             // [E]

  // ws layout: qt (N*128 u8) | sc (N f32) | z (N f32) |
  //            srcs,dsts,eids (E i32 each) | bins | offsets(NB+1) | cursors
  char* p = (char*)d_ws;
  unsigned* qt = (unsigned*)p;          p += (size_t)N * DIM;
  float* sc    = (float*)p;             p += (size_t)N * sizeof(float);
  float* z     = (float*)p;             p += (size_t)N * sizeof(float);
  int* srcs    = (int*)p;               p += (size_t)E * sizeof(int);
  int* dsts    = (int*)p;               p += (size_t)E * sizeof(int);
  int* eids    = (int*)p;               p += (size_t)E * sizeof(int);
  int* bins    = (int*)p;               p += NB * sizeof(int);
  int* offsets = (int*)p;               p += (NB + 1) * sizeof(int);
  int* cursors = (int*)p;               p += NB * sizeof(int);
  const size_t need_bucket = (size_t)(p - (char*)d_ws);
  const size_t need_q = (size_t)N * DIM + 2 * (size_t)N * sizeof(float);

  const bool use_bucket = (d_ws != nullptr) && (ws_size >= need_bucket);
  const bool use_q = (d_ws != nullptr) && (ws_size >= need_q);

  const int nblk = (N + 63) / 64;
  if (use_bucket) {
    hipMemsetAsync(bins, 0, NB * sizeof(int), stream);
    count_kernel<<<1024, 256, 0, stream>>>(ei, bins, E, N);
    scan_kernel<<<1, 64, 0, stream>>>(bins, offsets, cursors);
    transform_mfma<true><<<nblk, 256, 0, stream>>>(x, Wt, bt, Ws, selfo,
                                                   qt, sc, z, N);
    scatter_kernel<<<1024, 256, 0, stream>>>(ei, z, bs, esc, srcs, dsts,
                                             eids, cursors, E, N);
    edge_bucketed<<<2048, 256, 0, stream>>>(srcs, dsts, eids, qt, sc,
                                            offsets, bins, (f4*)merged);
  } else if (use_q) {
    transform_mfma<true><<<nblk, 256, 0, stream>>>(x, Wt, bt, Ws, selfo,
                                                   qt, sc, z, N);
    edge_kernel_q<<<8192, 256, 0, stream>>>(ei, qt, sc, z, bs,
                                            (f4*)merged, esc, E);
  } else {
    transform_mfma<false><<<nblk, 256, 0, stream>>>(x, Wt, bt, Ws, selfo,
                                                    nullptr, nullptr, nullptr, N);
    edge_kernel_f32<<<8192, 256, 0, stream>>>(ei, (const f4*)selfo, (f4*)merged, E);
    score_dot_kernel<<<4096, 256, 0, stream>>>(ei, selfo, Ws, bs, esc, E);
  }
}

// Round 10
// 217.304 us; speedup vs baseline: 1.9569x; 1.9569x over previous
//
#include <hip/hip_runtime.h>

typedef float f4 __attribute__((ext_vector_type(4)));
typedef unsigned short u16;
typedef unsigned char u8;
typedef u16 us4 __attribute__((ext_vector_type(4)));
typedef int i4 __attribute__((ext_vector_type(4)));
typedef __attribute__((ext_vector_type(4))) float f32x4;
typedef __attribute__((ext_vector_type(8))) short bf16x8;

#define DIM 128
#define DIM4 32

__device__ __forceinline__ u16 f32_to_bf16_rne(float f) {
  unsigned u = __float_as_uint(f);
  return (u16)((u + 0x7FFFu + ((u >> 16) & 1u)) >> 16);
}
__device__ __forceinline__ us4 f4_to_bf4(f4 v) {
  us4 h;
  h[0] = f32_to_bf16_rne(v[0]); h[1] = f32_to_bf16_rne(v[1]);
  h[2] = f32_to_bf16_rne(v[2]); h[3] = f32_to_bf16_rne(v[3]);
  return h;
}

// Kernel A (MFMA, fused quant): self[n] = 2*(x[n]@Wt^T)+bt (f32, final slot),
// z[n] = self[n].Ws, and per-row biased-uint8 table qt + scales sc quantized
// straight from the accumulators. Xb LDS reused for the quant repack.
template <bool QUANT>
__global__ __launch_bounds__(256) void transform_mfma(
    const float* __restrict__ x, const float* __restrict__ Wt,
    const float* __restrict__ bt, const float* __restrict__ Ws,
    float* __restrict__ self_out, unsigned* __restrict__ qt,
    float* __restrict__ sc, float* __restrict__ z, int N) {
  __shared__ u16 Wb[DIM * DIM];   // bf16 Wt (row-major, swizzled), 32 KB
  __shared__ u16 Xb[64 * DIM];    // bf16 x chunk (swizzled), 16 KB; reused as Q

  const int tid = threadIdx.x;
  const int base = blockIdx.x * 64;

  const f4* Wt4 = (const f4*)Wt;
  for (int i = tid; i < DIM * DIM4; i += 256) {
    int row = i >> 5, k4 = i & 31;
    *(us4*)&Wb[((row * DIM + k4 * 4) ^ ((row & 7) << 3))] = f4_to_bf4(Wt4[i]);
  }
  const f4* xg4 = (const f4*)x;
  for (int i = tid; i < 64 * DIM4; i += 256) {
    int row = i >> 5, k4 = i & 31;
    int g = base + row;
    f4 v = {0.f, 0.f, 0.f, 0.f};
    if (g < N) v = __builtin_nontemporal_load(&xg4[(size_t)g * DIM4 + k4]);
    *(us4*)&Xb[((row * DIM + k4 * 4) ^ ((row & 7) << 3))] = f4_to_bf4(v);
  }
  __syncthreads();

  const int lane = tid & 63;
  const int w = tid >> 6;        // wave 0..3 -> rows w*16..w*16+15
  const int rA = lane & 15;
  const int part = lane >> 4;    // 0..3

  f32x4 acc[8];
#pragma unroll
  for (int c = 0; c < 8; ++c) acc[c] = (f32x4){0.f, 0.f, 0.f, 0.f};

  const int xrow = w * 16 + rA;
  const int xswz = (xrow & 7) << 3;
#pragma unroll
  for (int s = 0; s < 4; ++s) {
    const int kofs = s * 32 + part * 8;
    bf16x8 a = *(const bf16x8*)&Xb[((xrow * DIM + kofs) ^ xswz)];
#pragma unroll
    for (int c = 0; c < 8; ++c) {
      const int wrow = c * 16 + rA;
      bf16x8 b = *(const bf16x8*)&Wb[((wrow * DIM + kofs) ^ ((wrow & 7) << 3))];
      acc[c] = __builtin_amdgcn_mfma_f32_16x16x32_bf16(a, b, acc[c], 0, 0, 0);
    }
  }

  float btv[8], wsv[8];
#pragma unroll
  for (int c = 0; c < 8; ++c) {
    btv[c] = bt[c * 16 + rA];
    wsv[c] = Ws[c * 16 + rA];
  }

  // v[r][c] at (row = w*16 + part*4 + r, col = c*16 + rA)
  float vv[4][8];
#pragma unroll
  for (int r = 0; r < 4; ++r)
#pragma unroll
    for (int c = 0; c < 8; ++c) vv[r][c] = 2.0f * acc[c][r] + btv[c];

#pragma unroll
  for (int r = 0; r < 4; ++r) {
    int g = base + w * 16 + part * 4 + r;
    if (g < N) {
      float zp = 0.f;
#pragma unroll
      for (int c = 0; c < 8; ++c) {
        self_out[(size_t)g * DIM + c * 16 + rA] = vv[r][c];
        zp += vv[r][c] * wsv[c];
      }
      zp += __shfl_xor(zp, 8);
      zp += __shfl_xor(zp, 4);
      zp += __shfl_xor(zp, 2);
      zp += __shfl_xor(zp, 1);
      if (rA == 0 && z != nullptr) z[g] = zp;
    }
  }

  if constexpr (QUANT) {
    __syncthreads();               // all waves done reading Xb -> reuse as Q
    u8* Qb = (u8*)Xb;              // [64][128] bytes
#pragma unroll
    for (int r = 0; r < 4; ++r) {
      const int rr = w * 16 + part * 4 + r;
      const int g = base + rr;
      float m = 0.f;
#pragma unroll
      for (int c = 0; c < 8; ++c) m = fmaxf(m, fabsf(vv[r][c]));
      m = fmaxf(m, __shfl_xor(m, 8));
      m = fmaxf(m, __shfl_xor(m, 4));
      m = fmaxf(m, __shfl_xor(m, 2));
      m = fmaxf(m, __shfl_xor(m, 1));
      const float inv = (m > 0.f) ? 127.0f / m : 0.f;
#pragma unroll
      for (int c = 0; c < 8; ++c) {
        int qv = __float2int_rn(vv[r][c] * inv) + 128;
        Qb[rr * DIM + c * 16 + rA] = (u8)qv;
      }
      if (rA == 0 && g < N) sc[g] = m * (1.0f / 127.0f);
    }
    __syncthreads();
    for (int i = tid; i < 64 * DIM4; i += 256) {
      int row = i >> 5, c4 = i & 31;
      int g = base + row;
      if (g < N)
        qt[(size_t)g * DIM4 + c4] = *(const unsigned*)&Qb[row * DIM + c4 * 4];
    }
  }
}

// Kernel B (fused score): merged[e] = 0.5*(self[src]+self[dst]) from the
// uint8 table; esc[e] = sigmoid(0.5*(z[s]+z[d]) + b_s) from the L2-resident
// z table using the already-loaded indices. 32 lanes/edge, 8 edges/group,
// all 16 row-gathers batch-issued, NT stores for merged, 2x16B esc stores.
__global__ __launch_bounds__(256) void edge_kernel_q(
    const int* __restrict__ ei, const unsigned* __restrict__ qt,
    const float* __restrict__ sc, const float* __restrict__ zt,
    const float* __restrict__ bs, f4* __restrict__ m4,
    float* __restrict__ esc, int E) {
  const int lane = threadIdx.x & 31;
  const int grp  = threadIdx.x >> 5;
  const float b0 = bs[0];
  const long long gstride = (long long)gridDim.x * 64;

  for (long long base = ((long long)blockIdx.x * 8 + grp) * 8; base < E;
       base += gstride) {
    if (base + 8 <= E) {
      i4 s0 = *(const i4*)&ei[base];
      i4 s1 = *(const i4*)&ei[base + 4];
      i4 d0 = *(const i4*)&ei[E + base];
      i4 d1 = *(const i4*)&ei[E + base + 4];
      int ss[8], dd[8];
#pragma unroll
      for (int u = 0; u < 4; ++u) {
        ss[u] = s0[u]; ss[u + 4] = s1[u];
        dd[u] = d0[u]; dd[u + 4] = d1[u];
      }
      unsigned ua[8], ub[8];
      float sa[8], sb[8], za[8], zb[8];
#pragma unroll
      for (int u = 0; u < 8; ++u) {
        ua[u] = qt[(size_t)ss[u] * DIM4 + lane];
        ub[u] = qt[(size_t)dd[u] * DIM4 + lane];
      }
#pragma unroll
      for (int u = 0; u < 8; ++u) {
        sa[u] = 0.5f * sc[ss[u]];
        sb[u] = 0.5f * sc[dd[u]];
      }
#pragma unroll
      for (int u = 0; u < 8; ++u) {
        za[u] = zt[ss[u]];
        zb[u] = zt[dd[u]];
      }
      float sval[8];
#pragma unroll
      for (int u = 0; u < 8; ++u) {
        float p = 0.5f * (za[u] + zb[u]) + b0;
        sval[u] = 1.0f / (1.0f + __expf(-p));
        const float off = -128.0f * (sa[u] + sb[u]);
        f4 m;
        m[0] = fmaf((float)(ua[u] & 0xffu), sa[u],
                    fmaf((float)(ub[u] & 0xffu), sb[u], off));
        m[1] = fmaf((float)((ua[u] >> 8) & 0xffu), sa[u],
                    fmaf((float)((ub[u] >> 8) & 0xffu), sb[u], off));
        m[2] = fmaf((float)((ua[u] >> 16) & 0xffu), sa[u],
                    fmaf((float)((ub[u] >> 16) & 0xffu), sb[u], off));
        m[3] = fmaf((float)(ua[u] >> 24), sa[u],
                    fmaf((float)(ub[u] >> 24), sb[u], off));
        __builtin_nontemporal_store(m, &m4[(size_t)(base + u) * DIM4 + lane]);
      }
      if (lane == 0) {
        f4 v0 = {sval[0], sval[1], sval[2], sval[3]};
        f4 v1 = {sval[4], sval[5], sval[6], sval[7]};
        *(f4*)&esc[base] = v0;
        *(f4*)&esc[base + 4] = v1;
      }
    } else {
      for (long long e = base; e < E; ++e) {
        int s = ei[e], d = ei[E + e];
        unsigned ua = qt[(size_t)s * DIM4 + lane];
        unsigned ub = qt[(size_t)d * DIM4 + lane];
        float sa = 0.5f * sc[s];
        float sb = 0.5f * sc[d];
        const float off = -128.0f * (sa + sb);
        f4 m;
        m[0] = fmaf((float)(ua & 0xffu), sa, fmaf((float)(ub & 0xffu), sb, off));
        m[1] = fmaf((float)((ua >> 8) & 0xffu), sa,
                    fmaf((float)((ub >> 8) & 0xffu), sb, off));
        m[2] = fmaf((float)((ua >> 16) & 0xffu), sa,
                    fmaf((float)((ub >> 16) & 0xffu), sb, off));
        m[3] = fmaf((float)(ua >> 24), sa, fmaf((float)(ub >> 24), sb, off));
        __builtin_nontemporal_store(m, &m4[(size_t)e * DIM4 + lane]);
        if (lane == 0) {
          float p = 0.5f * (zt[s] + zt[d]) + b0;
          esc[e] = 1.0f / (1.0f + __expf(-p));
        }
      }
    }
  }
}

// Fallback edge kernel (no workspace): f32 gather.
__global__ __launch_bounds__(256) void edge_kernel_f32(
    const int* __restrict__ ei, const f4* __restrict__ selff4,
    f4* __restrict__ m4, int E) {
  const int lane = threadIdx.x & 31;
  const int grp  = threadIdx.x >> 5;
  const long long gstride = (long long)gridDim.x * 32;
  for (long long base = ((long long)blockIdx.x * 8 + grp) * 4; base < E;
       base += gstride) {
    long long lim = (base + 4 <= E) ? base + 4 : (long long)E;
    for (long long e = base; e < lim; ++e) {
      int s = ei[e], d = ei[E + e];
      f4 a = selff4[(size_t)s * DIM4 + lane];
      f4 b = selff4[(size_t)d * DIM4 + lane];
      f4 m = 0.5f * (a + b);
      __builtin_nontemporal_store(m, &m4[(size_t)e * DIM4 + lane]);
    }
  }
}

// Fallback score (no ws): per-edge dot, 32 lanes/edge.
__global__ __launch_bounds__(256) void score_dot_kernel(
    const int* __restrict__ ei, const float* __restrict__ self,
    const float* __restrict__ Ws, const float* __restrict__ bs,
    float* __restrict__ esc, int E) {
  const int lane = threadIdx.x & 31;
  const int grp  = threadIdx.x >> 5;
  const f4* self4 = (const f4*)self;
  const f4 w = ((const f4*)Ws)[lane];
  const float b0 = bs[0];
  const long long stride = (long long)gridDim.x * 8;
  for (long long e = (long long)blockIdx.x * 8 + grp; e < E; e += stride) {
    int s = ei[e], d = ei[E + e];
    f4 a = self4[(size_t)s * DIM4 + lane];
    f4 b = self4[(size_t)d * DIM4 + lane];
    f4 m = 0.5f * (a + b);
    float p = m[0]*w[0] + m[1]*w[1] + m[2]*w[2] + m[3]*w[3];
    p += __shfl_xor(p, 16);
    p += __shfl_xor(p, 8);
    p += __shfl_xor(p, 4);
    p += __shfl_xor(p, 2);
    p += __shfl_xor(p, 1);
    if (lane == 0) esc[e] = 1.0f / (1.0f + __expf(-(p + b0)));
  }
}

extern "C" void kernel_launch(void* const* d_in, const int* in_sizes, int n_in,
                              void* d_out, int out_size, void* d_ws, size_t ws_size,
                              hipStream_t stream) {
  const float* x  = (const float*)d_in[0];
  const int*   ei = (const int*)d_in[1];
  // d_in[2] = batch (unused by the outputs)
  const float* Wt = (const float*)d_in[3];
  const float* bt = (const float*)d_in[4];
  const float* Ws = (const float*)d_in[5];
  const float* bs = (const float*)d_in[6];

  const int N = in_sizes[0] / DIM;
  const int E = in_sizes[1] / 2;

  float* merged = (float*)d_out;                       // [E,128]
  float* selfo  = merged + (size_t)E * DIM;            // [N,128]
  float* esc    = selfo + (size_t)N * DIM;             // [E]

  // ws layout: q table (N*128 u8) | scales (N f32) | z (N f32)
  const size_t need = (size_t)N * DIM + 2 * (size_t)N * sizeof(float);
  const bool use_q = (d_ws != nullptr) && (ws_size >= need);

  unsigned* qt = (unsigned*)d_ws;
  float* sc = (float*)((char*)d_ws + (size_t)N * DIM);
  float* z = sc + N;

  const int nblk = (N + 63) / 64;
  if (use_q) {
    transform_mfma<true><<<nblk, 256, 0, stream>>>(x, Wt, bt, Ws, selfo,
                                                   qt, sc, z, N);
    edge_kernel_q<<<8192, 256, 0, stream>>>(ei, qt, sc, z, bs,
                                            (f4*)merged, esc, E);
  } else {
    transform_mfma<false><<<nblk, 256, 0, stream>>>(x, Wt, bt, Ws, selfo,
                                                    nullptr, nullptr, nullptr, N);
    edge_kernel_f32<<<8192, 256, 0, stream>>>(ei, (const f4*)selfo, (f4*)merged, E);
    score_dot_kernel<<<4096, 256, 0, stream>>>(ei, selfo, Ws, bs, esc, E);
  }
}